// Round 12
// baseline (717.169 us; speedup 1.0000x reference)
//
#include <hip/hip_runtime.h>

// ---------------------------------------------------------------------------
// InputMapCTRNN: T=256, B=128, I=64, C=256, H=512, O=128, ALPHA=1, EPS=1e-5
//
// h[t,b,n] = relu( sum_c ctx[t,b,c]*S_c + S_bias ) -> one MFMA GEMM
//   M=32768,N=512,K=16448 with A[m,k]=ctx[m,k>>6]*x[m,k&63] generated
//   per-fragment in registers (f16 since R9).
//
// k_big history: R5/R7 bf16 456us (VALU 3371 + MFMA 4966 serialized).
//   R9 f16 (v_pk_mul_f16 scaling): 410us, MfmaUtil 63.5, VALU 30.3, VGPR 112,
//   ZERO spill. Residual VALU (2290cyc/SIMD/kk) ~4x static estimate ->
//   unhoisted swizzle address math + asm-mov overhead + serial scale->MFMA dep.
// R10/R11/R12 (R10,R11 = container-acquisition failures, never ran; infra
//   errors cluster temporally — resubmit unchanged): (1) hoist LDS read
//   bases: lbase[g] = l15*256 + (((g>>1)*8+(g&1)*4+quad)^l15)*16 precomputed;
//   per-read addr = p*32768 + lbase[g] + nt*4096 (imm-foldable) -> ~0
//   VALU/read. (2) software-pipeline scale8h one group ahead of its MFMAs ->
//   pk_mul runs in the MFMA shadow, not on its critical path. +16 live regs,
//   cap 256 -> no spill risk.
// ---------------------------------------------------------------------------

typedef unsigned int  uint_t;
typedef unsigned short ushort_t;
typedef __attribute__((ext_vector_type(8))) short  short8;
typedef __attribute__((ext_vector_type(4))) short  short4v;
typedef __attribute__((ext_vector_type(4))) float  floatx4;
typedef _Float16 half8 __attribute__((ext_vector_type(8)));

__device__ __forceinline__ ushort_t f2bf(float f) {
    uint_t u = __float_as_uint(f);
    u = (u + 0x7fffu + ((u >> 16) & 1u)) >> 16;   // RNE
    return (ushort_t)u;
}
__device__ __forceinline__ ushort_t f2h(float f) {
    union { _Float16 h; ushort_t u; } c;
    c.h = (_Float16)f;                             // v_cvt_f16_f32, RNE
    return c.u;
}
__device__ __forceinline__ uint_t pack2(float a, float b) {
    return (uint_t)f2bf(a) | ((uint_t)f2bf(b) << 16);
}
__device__ __forceinline__ float blo(uint_t u) { return __uint_as_float(u << 16); }
__device__ __forceinline__ float bhi(uint_t u) { return __uint_as_float(u & 0xffff0000u); }

__device__ __forceinline__ void glds16(const void* g, void* l) {
    __builtin_amdgcn_global_load_lds(
        (const __attribute__((address_space(1))) unsigned int*)g,
        (__attribute__((address_space(3))) unsigned int*)l, 16, 0, 0);
}

// barrier draining ONLY LDS ops; global stores/loads stay in flight.
__device__ __forceinline__ void barrier_lgkm() {
    asm volatile("s_waitcnt lgkmcnt(0)" ::: "memory");
    __builtin_amdgcn_s_barrier();
}

// f32 scalar -> packed f16 pair (s,s), 1 inst (RTZ; scale precision ample)
__device__ __forceinline__ uint_t bcast_h2(float s) {
    uint_t r;
    asm("v_cvt_pkrtz_f16_f32 %0, %1, %2" : "=v"(r) : "v"(s), "v"(s));
    return r;
}
// scale 8 packed f16 by f16x2 broadcast scalar: 4 x v_pk_mul_f16
__device__ __forceinline__ short8 scale8h(short8 a, uint_t s2) {
    union { short8 v; uint_t u[4]; } in, out;
    in.v = a;
#pragma unroll
    for (int q = 0; q < 4; ++q)
        asm("v_pk_mul_f16 %0, %1, %2" : "=v"(out.u[q]) : "v"(in.u[q]), "v"(s2));
    return out.v;
}
__device__ __forceinline__ half8 as_h8(short8 s) {
    union { short8 a; half8 b; } c; c.a = s; return c.b;
}

// ---------------------------------------------------------------------------
// FUSED (512 thr): blocks 0..7 = sequential ctx recurrence, 8 waves (2/SIMD).
// blocks 8..1051 = prep (WbT transpose -> F16, Whh/Who -> bf16, x -> F16).
// CTXT layout: CTXT2[c>>1][m][c&1] (pair-rows of 65536 floats).
// ---------------------------------------------------------------------------
__global__ __launch_bounds__(512, 2) void k_fused(
        const float* __restrict__ x, const float* __restrict__ Wcc,
        const float* __restrict__ bcc, const float* __restrict__ Wic,
        const float* __restrict__ bic, const float* __restrict__ Wmap,
        const float* __restrict__ bmap, const float* __restrict__ Whh,
        const float* __restrict__ Who,
        ushort_t* WbT, ushort_t* Whhb, ushort_t* Whob, ushort_t* xbf,
        float* __restrict__ CTXT, float* __restrict__ ctx_out) {
    __shared__ __align__(16) char smem[32896];   // union: prep 32896 B / rec 20480 B
    const int tid = threadIdx.x;
    const int bid = blockIdx.x;

    if (bid >= 8) {
        const int pb = bid - 8;
        if (pb < 512) {                      // WbT[n][c*64+i] = f16(Wmap[n*64+i][c])
            float* tl = (float*)smem;        // 32*257 floats
            const int n = pb;
            for (int p2 = 0; p2 < 2; ++p2) {
                if (p2) barrier_lgkm();
                if (tid < 256) {
#pragma unroll
                    for (int k = 0; k < 32; ++k)
                        tl[k * 257 + tid] = Wmap[(size_t)(n * 64 + p2 * 32 + k) * 256 + tid];
                }
                barrier_lgkm();
                if (tid < 256) {
#pragma unroll
                    for (int k2 = 0; k2 < 32; ++k2) {
                        int o = k2 * 256 + tid;
                        int il = o & 31, c = o >> 5;
                        WbT[(size_t)n * 16448 + c * 64 + p2 * 32 + il] = f2h(tl[il * 257 + c]);
                    }
                }
            }
            if (tid < 64) WbT[(size_t)n * 16448 + 16384 + tid] = f2h(bmap[n * 64 + tid]);
        } else if (pb < 528) {
            size_t base = (size_t)(pb - 512) * 16384;
#pragma unroll
            for (int k = 0; k < 32; ++k) { size_t i = base + k * 512 + tid; Whhb[i] = f2bf(Whh[i]); }
        } else if (pb < 532) {
            size_t base = (size_t)(pb - 528) * 16384;
#pragma unroll
            for (int k = 0; k < 32; ++k) { size_t i = base + k * 512 + tid; Whob[i] = f2bf(Who[i]); }
        } else {
            size_t base = (size_t)(pb - 532) * 4096;
#pragma unroll
            for (int k = 0; k < 8; ++k) { size_t i = base + k * 512 + tid; xbf[i] = f2h(x[i]); }
        }
        return;
    }

    // ---------------- recurrence: block g owns samples [g*16, g*16+16) ------
    // 8 waves; wave w owns output channels [w*32, w*32+32)  (mt = 0,1)
    char* bufs = smem;                          // 2 x 10240 B
    const int g = bid;
    const int lane = tid & 63, w = tid >> 6;
    const int l15 = lane & 15, quad = lane >> 4;
    const int bq = tid >> 4, o4 = tid & 15;     // x-staging role (tid<256)

    // A-fragments: Wcc (kb 0..7) + Wic (kb 8..9); row j = w*32+mt*16+l15
    short8 wf[2][8], wi[2][2];
#pragma unroll
    for (int mt = 0; mt < 2; ++mt) {
        const int j = w * 32 + mt * 16 + l15;
#pragma unroll
        for (int kb = 0; kb < 8; ++kb) {
            const float* src = Wcc + (size_t)j * 256 + kb * 32 + quad * 8;
            float4 a = *(const float4*)src;
            float4 b = *(const float4*)(src + 4);
            short8 s;
            s[0] = (short)f2bf(a.x); s[1] = (short)f2bf(a.y);
            s[2] = (short)f2bf(a.z); s[3] = (short)f2bf(a.w);
            s[4] = (short)f2bf(b.x); s[5] = (short)f2bf(b.y);
            s[6] = (short)f2bf(b.z); s[7] = (short)f2bf(b.w);
            wf[mt][kb] = s;
        }
#pragma unroll
        for (int kb = 0; kb < 2; ++kb) {
            const float* src = Wic + (size_t)j * 64 + kb * 32 + quad * 8;
            float4 a = *(const float4*)src;
            float4 b = *(const float4*)(src + 4);
            short8 s;
            s[0] = (short)f2bf(a.x); s[1] = (short)f2bf(a.y);
            s[2] = (short)f2bf(a.z); s[3] = (short)f2bf(a.w);
            s[4] = (short)f2bf(b.x); s[5] = (short)f2bf(b.y);
            s[6] = (short)f2bf(b.z); s[7] = (short)f2bf(b.w);
            wi[mt][kb] = s;
        }
    }
    float4 bias[2];
#pragma unroll
    for (int mt = 0; mt < 2; ++mt) {
        const int j0 = w * 32 + mt * 16 + quad * 4;
        float4 b1 = *(const float4*)(bic + j0);
        float4 b2 = *(const float4*)(bcc + j0);
        bias[mt] = (float4){b1.x + b2.x, b1.y + b2.y, b1.z + b2.z, b1.w + b2.w};
    }
    // init buf0: ctx=0 (rows 0..31 = 8192 B, one uint4 per thread), x_0
    *(uint4*)(bufs + tid * 16) = (uint4){0, 0, 0, 0};
    if (tid < 256) {
        float4 xv = *(const float4*)(x + (size_t)(g * 16 + bq) * 64 + o4 * 4);
        short4v s4;
        s4[0] = (short)f2bf(xv.x); s4[1] = (short)f2bf(xv.y);
        s4[2] = (short)f2bf(xv.z); s4[3] = (short)f2bf(xv.w);
        *(short4v*)(bufs + (32 + (o4 >> 1)) * 256 + bq * 16 + (o4 & 1) * 8) = s4;
    }
    float4 y[2];
#pragma unroll
    for (int mt = 0; mt < 2; ++mt) y[mt] = (float4){0.f, 0.f, 0.f, 0.f};
    // 2-step-ahead x pipeline: xv_n holds x[t+1] during step t
    float4 xv_n, xv_f;
    if (tid < 256)
        xv_n = *(const float4*)(x + (size_t)(128 + g * 16 + bq) * 64 + o4 * 4);
    barrier_lgkm();

    int p = 0;
#pragma unroll 1
    for (int t = 0; t < 256; ++t) {
        char* bp = bufs + p * 10240;
        char* bn = bufs + (p ^ 1) * 10240;
        // CTXT2[c>>1][m][c&1] = ctx entering step t (= y); m = t*128+g*16+l15
#pragma unroll
        for (int mt = 0; mt < 2; ++mt) {
            const int j0 = w * 32 + mt * 16 + quad * 4;     // multiple of 4
            const size_t mi = (size_t)(t * 128 + g * 16 + l15) * 2;
            const size_t pr = (size_t)(j0 >> 1) * 65536 + mi;
            *(float2*)(CTXT + pr)         = (float2){y[mt].x, y[mt].y};
            *(float2*)(CTXT + pr + 65536) = (float2){y[mt].z, y[mt].w};
        }
        if (t < 254 && tid < 256)                           // load x[t+2]
            xv_f = *(const float4*)(x + (size_t)((t + 2) * 128 + g * 16 + bq) * 64 + o4 * 4);
        floatx4 acc[2];
#pragma unroll
        for (int mt = 0; mt < 2; ++mt) acc[mt] = (floatx4){0.f, 0.f, 0.f, 0.f};
#pragma unroll
        for (int kb = 0; kb < 8; ++kb) {
            short8 bf = *(const short8*)(bp + (kb * 4 + quad) * 256 + l15 * 16);
#pragma unroll
            for (int mt = 0; mt < 2; ++mt)
                acc[mt] = __builtin_amdgcn_mfma_f32_16x16x32_bf16(wf[mt][kb], bf, acc[mt], 0, 0, 0);
        }
#pragma unroll
        for (int kb = 0; kb < 2; ++kb) {
            short8 bf = *(const short8*)(bp + ((8 + kb) * 4 + quad) * 256 + l15 * 16);
#pragma unroll
            for (int mt = 0; mt < 2; ++mt)
                acc[mt] = __builtin_amdgcn_mfma_f32_16x16x32_bf16(wi[mt][kb], bf, acc[mt], 0, 0, 0);
        }
#pragma unroll
        for (int mt = 0; mt < 2; ++mt) {
            y[mt].x = fmaxf(acc[mt][0] + bias[mt].x, 0.f);
            y[mt].y = fmaxf(acc[mt][1] + bias[mt].y, 0.f);
            y[mt].z = fmaxf(acc[mt][2] + bias[mt].z, 0.f);
            y[mt].w = fmaxf(acc[mt][3] + bias[mt].w, 0.f);
        }
        if (t < 255) {
#pragma unroll
            for (int mt = 0; mt < 2; ++mt) {
                const int c0 = w * 32 + mt * 16 + quad * 4;
                short4v s4;
                s4[0] = (short)f2bf(y[mt].x); s4[1] = (short)f2bf(y[mt].y);
                s4[2] = (short)f2bf(y[mt].z); s4[3] = (short)f2bf(y[mt].w);
                *(short4v*)(bn + (c0 >> 3) * 256 + l15 * 16 + (c0 & 7) * 2) = s4;
            }
            if (tid < 256) {
                short4v s4;
                s4[0] = (short)f2bf(xv_n.x); s4[1] = (short)f2bf(xv_n.y);
                s4[2] = (short)f2bf(xv_n.z); s4[3] = (short)f2bf(xv_n.w);
                *(short4v*)(bn + (32 + (o4 >> 1)) * 256 + bq * 16 + (o4 & 1) * 8) = s4;
            }
        }
        barrier_lgkm();
        p ^= 1;
        xv_n = xv_f;
    }
#pragma unroll
    for (int mt = 0; mt < 2; ++mt) {
        const int j0 = w * 32 + mt * 16 + quad * 4;
#pragma unroll
        for (int r = 0; r < 4; ++r)
            ctx_out[(size_t)(g * 16 + l15) * 256 + j0 + r] = (&y[mt].x)[r];
    }
}

// ---------------------------------------------------------------------------
// BIG GEMM (FP16 A/B): M=32768,N=512,K=16448, scale folded into A-fragments.
// 256 thr / 4 waves, block tile 256x128, wave tile 64m x 128n (mt=4).
// BK=128, LDS dbuf (2x32 KB), glds(16B) prefetch, grid 512 (2 blocks/CU),
// XCD swizzle by=gidx&3.
// R10: hoisted LDS read bases (lbase[g], per-read addr = p*32768 + lbase[g]
// + nt*4096 imm) and software-pipelined scale8h one group ahead of its
// MFMA cluster (pk_mul runs in MFMA shadow). Groups g = h*2+ks.
// ---------------------------------------------------------------------------
__global__ __launch_bounds__(256, 2) void k_big(const ushort_t* __restrict__ xbf,
                                                const ushort_t* __restrict__ WbT,
                                                const float* __restrict__ CTXT,
                                                ushort_t* __restrict__ hbf) {
    __shared__ __align__(16) ushort_t Bt[2 * 128 * 128];   // 64 KB
    const int tid = threadIdx.x;
    const int lane = tid & 63, w = tid >> 6;               // 4 waves
    const int l15 = lane & 15, quad = lane >> 4;
    const int gidx = blockIdx.x;
    const int by = gidx & 3;                               // xcd = gidx&7
    const int bx = (gidx >> 3) * 2 + ((gidx >> 2) & 1);    // 0..127
    const int m0 = bx * 256, n0 = by * 128;
    const int mrb = m0 + w * 64 + l15;                     // mt=0 A-row

    short8 afr[4][2];                                      // [mt][ks]: f16 x row frag
#pragma unroll
    for (int mt = 0; mt < 4; ++mt) {
        afr[mt][0] = *(const short8*)(xbf + (size_t)(mrb + mt * 16) * 64 + quad * 8);
        afr[mt][1] = *(const short8*)(xbf + (size_t)(mrb + mt * 16) * 64 + 32 + quad * 8);
    }

    floatx4 acc[4][8];
#pragma unroll
    for (int mt = 0; mt < 4; ++mt)
#pragma unroll
        for (int nt = 0; nt < 8; ++nt) acc[mt][nt] = (floatx4){0.f, 0.f, 0.f, 0.f};

    // hoisted LDS read bases: byte addr = p*32768 + lbase[g] + nt*4096,
    // lbase[g] = l15*256 + (((g>>1)*8 + (g&1)*4 + quad) ^ l15)*16
    uint_t lbase[4];
#pragma unroll
    for (int g2 = 0; g2 < 4; ++g2)
        lbase[g2] = (uint_t)(l15 * 256 + ((((g2 >> 1) * 8 + (g2 & 1) * 4 + quad) ^ l15) * 16));

    // staging: granule G = q*256 + tid (q 0..7); nr = q*16 + (tid>>4),
    // slot k8 = l15 ^ (tid>>4) — same for all q -> one pointer.
    const int r0 = tid >> 4;                               // 0..15
    const ushort_t* gq0 = WbT + (size_t)(n0 + r0) * 16448 + (size_t)(l15 ^ r0) * 8;
    const size_t QSH16 = (size_t)16 * 16448;               // +16 rows (ushorts)
    ushort_t* lqb = Bt + w * 512;                          // wave-uniform base
#pragma unroll
    for (int q = 0; q < 8; ++q)                            // tile 0 -> buf 0
        glds16(gq0 + q * QSH16, lqb + q * 2048);

    // scales, packed f16x2 broadcast: s2[mt][h]
    uint_t s2[4][2];
    {
        const float* cp0 = CTXT + (size_t)mrb * 2;
#pragma unroll
        for (int mt = 0; mt < 4; ++mt) {
            float2 sc = *(const float2*)(cp0 + mt * 32);
            s2[mt][0] = bcast_h2(sc.x);
            s2[mt][1] = bcast_h2(sc.y);
        }
    }
    const float* cps = CTXT + (size_t)mrb * 2 + 65536;     // next pair-row

    const ushort_t* gqk = gq0;                             // moving K pointer
    for (int kk = 0; kk < 129; ++kk) {
        const int p = kk & 1;
        __syncthreads();                                   // tile kk resident
        if (kk < 128) {                                    // prefetch tile kk+1
            gqk += 128;
            ushort_t* ln_ = Bt + (p ^ 1) * 16384 + w * 512;
#pragma unroll
            for (int q = 0; q < 8; ++q)
                glds16(gqk + q * QSH16, ln_ + q * 2048);
        }
        uint_t s2n[4][2];
        if (kk + 1 < 128) {
#pragma unroll
            for (int mt = 0; mt < 4; ++mt) {
                float2 sc = *(const float2*)(cps + mt * 32);
                s2n[mt][0] = bcast_h2(sc.x);
                s2n[mt][1] = bcast_h2(sc.y);
            }
            cps += 65536;
        } else {
#pragma unroll
            for (int mt = 0; mt < 4; ++mt) { s2n[mt][0] = 0x3c003c00u; s2n[mt][1] = 0x3c003c00u; }
        }
        const char* bbase = (const char*)Bt + (p << 15);   // p*32768
        if (kk < 128) {
            // software pipeline: scale group g+1 while group g's MFMAs issue
            short8 a0 = scale8h(afr[0][0], s2[0][0]);
            short8 a1 = scale8h(afr[1][0], s2[1][0]);
            short8 a2 = scale8h(afr[2][0], s2[2][0]);
            short8 a3 = scale8h(afr[3][0], s2[3][0]);
#pragma unroll
            for (int g2 = 0; g2 < 4; ++g2) {
                short8 n0_, n1_, n2_, n3_;
                if (g2 < 3) {
                    const int gn = g2 + 1, hn = gn >> 1, ksn = gn & 1;
                    n0_ = scale8h(afr[0][ksn], s2[0][hn]);
                    n1_ = scale8h(afr[1][ksn], s2[1][hn]);
                    n2_ = scale8h(afr[2][ksn], s2[2][hn]);
                    n3_ = scale8h(afr[3][ksn], s2[3][hn]);
                }
                const char* bg = bbase + lbase[g2];
#pragma unroll
                for (int nt = 0; nt < 8; ++nt) {
                    short8 b = *(const short8*)(bg + nt * 4096);
                    acc[0][nt] = __builtin_amdgcn_mfma_f32_16x16x32_f16(as_h8(a0), as_h8(b), acc[0][nt], 0, 0, 0);
                    acc[1][nt] = __builtin_amdgcn_mfma_f32_16x16x32_f16(as_h8(a1), as_h8(b), acc[1][nt], 0, 0, 0);
                    acc[2][nt] = __builtin_amdgcn_mfma_f32_16x16x32_f16(as_h8(a2), as_h8(b), acc[2][nt], 0, 0, 0);
                    acc[3][nt] = __builtin_amdgcn_mfma_f32_16x16x32_f16(as_h8(a3), as_h8(b), acc[3][nt], 0, 0, 0);
                }
                if (g2 < 3) { a0 = n0_; a1 = n1_; a2 = n2_; a3 = n3_; }
            }
        } else {                                           // bias block, scale=1
#pragma unroll
            for (int ks = 0; ks < 2; ++ks) {
                const char* bg = bbase + lbase[ks];        // g=ks (h=0)
#pragma unroll
                for (int nt = 0; nt < 8; ++nt) {
                    short8 b = *(const short8*)(bg + nt * 4096);
#pragma unroll
                    for (int mt = 0; mt < 4; ++mt)
                        acc[mt][nt] = __builtin_amdgcn_mfma_f32_16x16x32_f16(as_h8(afr[mt][ks]), as_h8(b), acc[mt][nt], 0, 0, 0);
                }
            }
        }
#pragma unroll
        for (int mt = 0; mt < 4; ++mt) { s2[mt][0] = s2n[mt][0]; s2[mt][1] = s2n[mt][1]; }
    }
    // epilogue: C/D col = n0+nt*16+l15, row = m0 + w*64 + mt*16 + quad*4 + r
#pragma unroll
    for (int mt = 0; mt < 4; ++mt)
#pragma unroll
        for (int nt = 0; nt < 8; ++nt) {
            const int col = n0 + nt * 16 + l15;
#pragma unroll
            for (int r = 0; r < 4; ++r) {
                const int row = m0 + w * 64 + mt * 16 + quad * 4 + r;
                hbf[(size_t)row * 512 + col] = f2bf(fmaxf(acc[mt][nt][r], 0.f));
            }
        }
}

// ---------------------------------------------------------------------------
// Generic bf16 NT GEMM: C[m,n] = sum_k A[m,k]*B[n,k] + bias[n]
// ---------------------------------------------------------------------------
template <bool OUTF32>
__global__ __launch_bounds__(256, 2) void k_gemm_nt(const ushort_t* __restrict__ A,
                                                    const ushort_t* __restrict__ Bm,
                                                    const float* __restrict__ bias,
                                                    ushort_t* __restrict__ outb,
                                                    float* __restrict__ outf,
                                                    int K, int Nst) {
    __shared__ __align__(16) ushort_t At[128 * 72];
    __shared__ __align__(16) ushort_t Bt[128 * 72];
    const int tid = threadIdx.x;
    const int lane = tid & 63, w = tid >> 6;
    const int wm = w & 1, wn = w >> 1;
    const int l15 = lane & 15, quad = lane >> 4;
    const int m0 = blockIdx.x * 128, n0 = blockIdx.y * 128;

    const int r_l = tid >> 1, kh = (tid & 1) * 32;
    const ushort_t* gA = A + (size_t)(m0 + r_l) * K + kh;
    const ushort_t* gB = Bm + (size_t)(n0 + r_l) * K + kh;
    ushort_t* lA = &At[r_l * 72 + kh];
    ushort_t* lB = &Bt[r_l * 72 + kh];

    uint4 ra0 = *(const uint4*)(gA + 0), ra1 = *(const uint4*)(gA + 8);
    uint4 ra2 = *(const uint4*)(gA + 16), ra3 = *(const uint4*)(gA + 24);
    uint4 rb0 = *(const uint4*)(gB + 0), rb1 = *(const uint4*)(gB + 8);
    uint4 rb2 = *(const uint4*)(gB + 16), rb3 = *(const uint4*)(gB + 24);

    floatx4 acc[4][4];
#pragma unroll
    for (int i = 0; i < 4; ++i)
#pragma unroll
        for (int j = 0; j < 4; ++j) acc[i][j] = (floatx4){0.f, 0.f, 0.f, 0.f};

    const int niter = K >> 6;
    for (int kb = 0; kb < niter; ++kb) {
        __syncthreads();
        *(uint4*)(lA + 0) = ra0;  *(uint4*)(lA + 8) = ra1;
        *(uint4*)(lA + 16) = ra2; *(uint4*)(lA + 24) = ra3;
        *(uint4*)(lB + 0) = rb0;  *(uint4*)(lB + 8) = rb1;
        *(uint4*)(lB + 16) = rb2; *(uint4*)(lB + 24) = rb3;
        __syncthreads();
        if (kb + 1 < niter) {
            const ushort_t* ga = gA + (size_t)(kb + 1) * 64;
            const ushort_t* gb = gB + (size_t)(kb + 1) * 64;
            ra0 = *(const uint4*)(ga + 0);  ra1 = *(const uint4*)(ga + 8);
            ra2 = *(const uint4*)(ga + 16); ra3 = *(const uint4*)(ga + 24);
            rb0 = *(const uint4*)(gb + 0);  rb1 = *(const uint4*)(gb + 8);
            rb2 = *(const uint4*)(gb + 16); rb3 = *(const uint4*)(gb + 24);
        }
        short8 av[4][2];
#pragma unroll
        for (int mt = 0; mt < 4; ++mt) {
            const int mr2 = wm * 64 + mt * 16 + l15;
            av[mt][0] = *(const short8*)(&At[mr2 * 72 + quad * 8]);
            av[mt][1] = *(const short8*)(&At[mr2 * 72 + 32 + quad * 8]);
        }
#pragma unroll
        for (int nt = 0; nt < 4; ++nt) {
            const int nr = wn * 64 + nt * 16 + l15;
            short8 b0 = *(const short8*)(&Bt[nr * 72 + quad * 8]);
            short8 b1 = *(const short8*)(&Bt[nr * 72 + 32 + quad * 8]);
#pragma unroll
            for (int mt = 0; mt < 4; ++mt) {
                acc[mt][nt] = __builtin_amdgcn_mfma_f32_16x16x32_bf16(av[mt][0], b0, acc[mt][nt], 0, 0, 0);
                acc[mt][nt] = __builtin_amdgcn_mfma_f32_16x16x32_bf16(av[mt][1], b1, acc[mt][nt], 0, 0, 0);
            }
        }
    }
#pragma unroll
    for (int mt = 0; mt < 4; ++mt)
#pragma unroll
        for (int nt = 0; nt < 4; ++nt) {
            const int col = n0 + wn * 64 + nt * 16 + l15;
            const float bb = bias[col];
#pragma unroll
            for (int r = 0; r < 4; ++r) {
                const int row = m0 + wm * 64 + mt * 16 + quad * 4 + r;
                const float v = acc[mt][nt][r] + bb;
                if (OUTF32) outf[(size_t)row * Nst + col] = v;
                else        outb[(size_t)row * Nst + col] = f2bf(v);
            }
        }
}

// ---------------------------------------------------------------------------
// LayerNorm + residual: z = h + relu( LN(hn)*g + b ), in-place over hbf.
// ---------------------------------------------------------------------------
__global__ __launch_bounds__(256, 1) void k_ln(const ushort_t* __restrict__ hn,
                                               ushort_t* __restrict__ h,
                                               const float* __restrict__ g,
                                               const float* __restrict__ bb) {
    const int tid = threadIdx.x;
    const int lane = tid & 63;
    const int row = blockIdx.x * 4 + (tid >> 6);
    const uint4 hv = *(const uint4*)(hn + (size_t)row * 512 + lane * 8);
    float f[8];
    f[0] = blo(hv.x); f[1] = bhi(hv.x); f[2] = blo(hv.y); f[3] = bhi(hv.y);
    f[4] = blo(hv.z); f[5] = bhi(hv.z); f[6] = blo(hv.w); f[7] = bhi(hv.w);
    float s = 0.f, s2 = 0.f;
#pragma unroll
    for (int j = 0; j < 8; ++j) { s += f[j]; s2 = fmaf(f[j], f[j], s2); }
#pragma unroll
    for (int o = 32; o >= 1; o >>= 1) { s += __shfl_xor(s, o, 64); s2 += __shfl_xor(s2, o, 64); }
    const float mu = s * (1.f / 512.f);
    const float var = s2 * (1.f / 512.f) - mu * mu;
    const float rs = rsqrtf(var + 1e-5f);
    const uint4 hh = *(const uint4*)(h + (size_t)row * 512 + lane * 8);
    float hf[8];
    hf[0] = blo(hh.x); hf[1] = bhi(hh.x); hf[2] = blo(hh.y); hf[3] = bhi(hh.y);
    hf[4] = blo(hh.z); hf[5] = bhi(hh.z); hf[6] = blo(hh.w); hf[7] = bhi(hh.w);
    float4 g0 = *(const float4*)(g + lane * 8);  float4 g1 = *(const float4*)(g + lane * 8 + 4);
    float4 b0 = *(const float4*)(bb + lane * 8); float4 b1 = *(const float4*)(bb + lane * 8 + 4);
    const float gv[8] = {g0.x, g0.y, g0.z, g0.w, g1.x, g1.y, g1.z, g1.w};
    const float bv[8] = {b0.x, b0.y, b0.z, b0.w, b1.x, b1.y, b1.z, b1.w};
    float z[8];
#pragma unroll
    for (int j = 0; j < 8; ++j)
        z[j] = hf[j] + fmaxf((f[j] - mu) * rs * gv[j] + bv[j], 0.f);
    uint4 o;
    o.x = pack2(z[0], z[1]); o.y = pack2(z[2], z[3]);
    o.z = pack2(z[4], z[5]); o.w = pack2(z[6], z[7]);
    *(uint4*)(h + (size_t)row * 512 + lane * 8) = o;
}

// ---------------------------------------------------------------------------
extern "C" void kernel_launch(void* const* d_in, const int* in_sizes, int n_in,
                              void* d_out, int out_size, void* d_ws, size_t ws_size,
                              hipStream_t stream) {
    const float* x    = (const float*)d_in[0];
    const float* Wcc  = (const float*)d_in[1];
    const float* bcc  = (const float*)d_in[2];
    const float* Wic  = (const float*)d_in[3];
    const float* bic  = (const float*)d_in[4];
    const float* Wmap = (const float*)d_in[5];
    const float* bmap = (const float*)d_in[6];
    const float* Whh  = (const float*)d_in[7];
    const float* bhh  = (const float*)d_in[8];
    const float* ln_g = (const float*)d_in[9];
    const float* ln_b = (const float*)d_in[10];
    const float* Who  = (const float*)d_in[11];
    const float* bho  = (const float*)d_in[12];
    float* out = (float*)d_out;

    char* wsb = (char*)d_ws;
    ushort_t* WbT  = (ushort_t*)(wsb);                    // 16,842,752 B + 1 KB pad (f16)
    ushort_t* Whhb = (ushort_t*)(wsb + 16843776);         //    524,288 (bf16)
    ushort_t* Whob = (ushort_t*)(wsb + 17368064);         //    131,072 (bf16)
    ushort_t* xbf  = (ushort_t*)(wsb + 17499136);         //  4,194,304 (f16)
    float*    CTXT = (float*)   (wsb + 21693440);         // 33,554,432 (pair layout)
    ushort_t* hbf  = (ushort_t*)(wsb + 55247872);         // 33,554,432 (h, then z)
    ushort_t* hnbf = (ushort_t*)(wsb + 88802304);         // 33,554,432 -> ~122 MB

    k_fused<<<1052, 512, 0, stream>>>(x, Wcc, bcc, Wic, bic, Wmap, bmap, Whh, Who,
                                      WbT, Whhb, Whob, xbf, CTXT, out + 4194304);
    k_big<<<512, 256, 0, stream>>>(xbf, WbT, CTXT, hbf);
    k_gemm_nt<false><<<dim3(256, 4), 256, 0, stream>>>(hbf, Whhb, bhh, hnbf, nullptr, 512, 512);
    k_ln<<<8192, 256, 0, stream>>>(hnbf, hbf, ln_g, ln_b);
    k_gemm_nt<true><<<dim3(256, 1), 256, 0, stream>>>(hbf, Whob, bho, nullptr, out, 512, 128);
}

// Round 13
// 706.012 us; speedup vs baseline: 1.0158x; 1.0158x over previous
//
#include <hip/hip_runtime.h>

// ---------------------------------------------------------------------------
// InputMapCTRNN: T=256, B=128, I=64, C=256, H=512, O=128, ALPHA=1, EPS=1e-5
//
// h[t,b,n] = relu( sum_c ctx[t,b,c]*S_c + S_bias ) -> one MFMA GEMM
//   M=32768,N=512,K=16448 with A[m,k]=ctx[m,k>>6]*x[m,k&63] generated
//   per-fragment in registers (f16 since R9).
//
// k_big: R9 f16 410us -> R12 (hoisted bases + scale pipeline) 407us, neutral.
//   MfmaUtil 66 + VALU 31 ~= 97% across all rounds -> issue-saturated at this
//   decomposition; 128-AGPR acc blocks higher waves/SIMD. FROZEN at 407.
// k_fused (~200us, 1875cyc/step vs ~700 issue): dominant latency = 10-deep
//   dependent MFMA accumulation chain (~400cyc) only partly hidden at
//   2 waves/SIMD.
// R13: k_fused only: (1) split accumulators even/odd kb -> two 5-deep chains
//   per mt (4 independent chains/wave); merge with one add. (2) y/x bf16
//   packing via v_cvt_pk_bf16_f32 (1 inst/pair vs ~6) on the pre-barrier
//   critical path.
// ---------------------------------------------------------------------------

typedef unsigned int  uint_t;
typedef unsigned short ushort_t;
typedef __attribute__((ext_vector_type(8))) short  short8;
typedef __attribute__((ext_vector_type(4))) short  short4v;
typedef __attribute__((ext_vector_type(4))) float  floatx4;
typedef _Float16 half8 __attribute__((ext_vector_type(8)));

__device__ __forceinline__ ushort_t f2bf(float f) {
    uint_t u = __float_as_uint(f);
    u = (u + 0x7fffu + ((u >> 16) & 1u)) >> 16;   // RNE
    return (ushort_t)u;
}
__device__ __forceinline__ ushort_t f2h(float f) {
    union { _Float16 h; ushort_t u; } c;
    c.h = (_Float16)f;                             // v_cvt_f16_f32, RNE
    return c.u;
}
__device__ __forceinline__ uint_t pack2(float a, float b) {
    return (uint_t)f2bf(a) | ((uint_t)f2bf(b) << 16);
}
__device__ __forceinline__ float blo(uint_t u) { return __uint_as_float(u << 16); }
__device__ __forceinline__ float bhi(uint_t u) { return __uint_as_float(u & 0xffff0000u); }

__device__ __forceinline__ void glds16(const void* g, void* l) {
    __builtin_amdgcn_global_load_lds(
        (const __attribute__((address_space(1))) unsigned int*)g,
        (__attribute__((address_space(3))) unsigned int*)l, 16, 0, 0);
}

// barrier draining ONLY LDS ops; global stores/loads stay in flight.
__device__ __forceinline__ void barrier_lgkm() {
    asm volatile("s_waitcnt lgkmcnt(0)" ::: "memory");
    __builtin_amdgcn_s_barrier();
}

// two f32 -> packed bf16 pair, 1 inst (RNE)
__device__ __forceinline__ uint_t cvtpk_bf16(float a, float b) {
    uint_t r;
    asm("v_cvt_pk_bf16_f32 %0, %1, %2" : "=v"(r) : "v"(a), "v"(b));
    return r;
}
// f32 scalar -> packed f16 pair (s,s), 1 inst (RTZ; scale precision ample)
__device__ __forceinline__ uint_t bcast_h2(float s) {
    uint_t r;
    asm("v_cvt_pkrtz_f16_f32 %0, %1, %2" : "=v"(r) : "v"(s), "v"(s));
    return r;
}
// scale 8 packed f16 by f16x2 broadcast scalar: 4 x v_pk_mul_f16
__device__ __forceinline__ short8 scale8h(short8 a, uint_t s2) {
    union { short8 v; uint_t u[4]; } in, out;
    in.v = a;
#pragma unroll
    for (int q = 0; q < 4; ++q)
        asm("v_pk_mul_f16 %0, %1, %2" : "=v"(out.u[q]) : "v"(in.u[q]), "v"(s2));
    return out.v;
}
__device__ __forceinline__ half8 as_h8(short8 s) {
    union { short8 a; half8 b; } c; c.a = s; return c.b;
}

// ---------------------------------------------------------------------------
// FUSED (512 thr): blocks 0..7 = sequential ctx recurrence, 8 waves (2/SIMD).
// blocks 8..1051 = prep (WbT transpose -> F16, Whh/Who -> bf16, x -> F16).
// CTXT layout: CTXT2[c>>1][m][c&1] (pair-rows of 65536 floats).
// ---------------------------------------------------------------------------
__global__ __launch_bounds__(512, 2) void k_fused(
        const float* __restrict__ x, const float* __restrict__ Wcc,
        const float* __restrict__ bcc, const float* __restrict__ Wic,
        const float* __restrict__ bic, const float* __restrict__ Wmap,
        const float* __restrict__ bmap, const float* __restrict__ Whh,
        const float* __restrict__ Who,
        ushort_t* WbT, ushort_t* Whhb, ushort_t* Whob, ushort_t* xbf,
        float* __restrict__ CTXT, float* __restrict__ ctx_out) {
    __shared__ __align__(16) char smem[32896];   // union: prep 32896 B / rec 20480 B
    const int tid = threadIdx.x;
    const int bid = blockIdx.x;

    if (bid >= 8) {
        const int pb = bid - 8;
        if (pb < 512) {                      // WbT[n][c*64+i] = f16(Wmap[n*64+i][c])
            float* tl = (float*)smem;        // 32*257 floats
            const int n = pb;
            for (int p2 = 0; p2 < 2; ++p2) {
                if (p2) barrier_lgkm();
                if (tid < 256) {
#pragma unroll
                    for (int k = 0; k < 32; ++k)
                        tl[k * 257 + tid] = Wmap[(size_t)(n * 64 + p2 * 32 + k) * 256 + tid];
                }
                barrier_lgkm();
                if (tid < 256) {
#pragma unroll
                    for (int k2 = 0; k2 < 32; ++k2) {
                        int o = k2 * 256 + tid;
                        int il = o & 31, c = o >> 5;
                        WbT[(size_t)n * 16448 + c * 64 + p2 * 32 + il] = f2h(tl[il * 257 + c]);
                    }
                }
            }
            if (tid < 64) WbT[(size_t)n * 16448 + 16384 + tid] = f2h(bmap[n * 64 + tid]);
        } else if (pb < 528) {
            size_t base = (size_t)(pb - 512) * 16384;
#pragma unroll
            for (int k = 0; k < 32; ++k) { size_t i = base + k * 512 + tid; Whhb[i] = f2bf(Whh[i]); }
        } else if (pb < 532) {
            size_t base = (size_t)(pb - 528) * 16384;
#pragma unroll
            for (int k = 0; k < 32; ++k) { size_t i = base + k * 512 + tid; Whob[i] = f2bf(Who[i]); }
        } else {
            size_t base = (size_t)(pb - 532) * 4096;
#pragma unroll
            for (int k = 0; k < 8; ++k) { size_t i = base + k * 512 + tid; xbf[i] = f2h(x[i]); }
        }
        return;
    }

    // ---------------- recurrence: block g owns samples [g*16, g*16+16) ------
    // 8 waves; wave w owns output channels [w*32, w*32+32)  (mt = 0,1)
    char* bufs = smem;                          // 2 x 10240 B
    const int g = bid;
    const int lane = tid & 63, w = tid >> 6;
    const int l15 = lane & 15, quad = lane >> 4;
    const int bq = tid >> 4, o4 = tid & 15;     // x-staging role (tid<256)

    // A-fragments: Wcc (kb 0..7) + Wic (kb 8..9); row j = w*32+mt*16+l15
    short8 wf[2][8], wi[2][2];
#pragma unroll
    for (int mt = 0; mt < 2; ++mt) {
        const int j = w * 32 + mt * 16 + l15;
#pragma unroll
        for (int kb = 0; kb < 8; ++kb) {
            const float* src = Wcc + (size_t)j * 256 + kb * 32 + quad * 8;
            float4 a = *(const float4*)src;
            float4 b = *(const float4*)(src + 4);
            short8 s;
            s[0] = (short)f2bf(a.x); s[1] = (short)f2bf(a.y);
            s[2] = (short)f2bf(a.z); s[3] = (short)f2bf(a.w);
            s[4] = (short)f2bf(b.x); s[5] = (short)f2bf(b.y);
            s[6] = (short)f2bf(b.z); s[7] = (short)f2bf(b.w);
            wf[mt][kb] = s;
        }
#pragma unroll
        for (int kb = 0; kb < 2; ++kb) {
            const float* src = Wic + (size_t)j * 64 + kb * 32 + quad * 8;
            float4 a = *(const float4*)src;
            float4 b = *(const float4*)(src + 4);
            short8 s;
            s[0] = (short)f2bf(a.x); s[1] = (short)f2bf(a.y);
            s[2] = (short)f2bf(a.z); s[3] = (short)f2bf(a.w);
            s[4] = (short)f2bf(b.x); s[5] = (short)f2bf(b.y);
            s[6] = (short)f2bf(b.z); s[7] = (short)f2bf(b.w);
            wi[mt][kb] = s;
        }
    }
    float4 bias[2];
#pragma unroll
    for (int mt = 0; mt < 2; ++mt) {
        const int j0 = w * 32 + mt * 16 + quad * 4;
        float4 b1 = *(const float4*)(bic + j0);
        float4 b2 = *(const float4*)(bcc + j0);
        bias[mt] = (float4){b1.x + b2.x, b1.y + b2.y, b1.z + b2.z, b1.w + b2.w};
    }
    // init buf0: ctx=0 (rows 0..31 = 8192 B, one uint4 per thread), x_0
    *(uint4*)(bufs + tid * 16) = (uint4){0, 0, 0, 0};
    if (tid < 256) {
        float4 xv = *(const float4*)(x + (size_t)(g * 16 + bq) * 64 + o4 * 4);
        uint2 u2;
        u2.x = cvtpk_bf16(xv.x, xv.y);
        u2.y = cvtpk_bf16(xv.z, xv.w);
        *(uint2*)(bufs + (32 + (o4 >> 1)) * 256 + bq * 16 + (o4 & 1) * 8) = u2;
    }
    float4 y[2];
#pragma unroll
    for (int mt = 0; mt < 2; ++mt) y[mt] = (float4){0.f, 0.f, 0.f, 0.f};
    // 2-step-ahead x pipeline: xv_n holds x[t+1] during step t
    float4 xv_n, xv_f;
    if (tid < 256)
        xv_n = *(const float4*)(x + (size_t)(128 + g * 16 + bq) * 64 + o4 * 4);
    barrier_lgkm();

    int p = 0;
#pragma unroll 1
    for (int t = 0; t < 256; ++t) {
        char* bp = bufs + p * 10240;
        char* bn = bufs + (p ^ 1) * 10240;
        // CTXT2[c>>1][m][c&1] = ctx entering step t (= y); m = t*128+g*16+l15
#pragma unroll
        for (int mt = 0; mt < 2; ++mt) {
            const int j0 = w * 32 + mt * 16 + quad * 4;     // multiple of 4
            const size_t mi = (size_t)(t * 128 + g * 16 + l15) * 2;
            const size_t pr = (size_t)(j0 >> 1) * 65536 + mi;
            *(float2*)(CTXT + pr)         = (float2){y[mt].x, y[mt].y};
            *(float2*)(CTXT + pr + 65536) = (float2){y[mt].z, y[mt].w};
        }
        if (t < 254 && tid < 256)                           // load x[t+2]
            xv_f = *(const float4*)(x + (size_t)((t + 2) * 128 + g * 16 + bq) * 64 + o4 * 4);
        // split accumulators: even kb -> acc0, odd kb -> acc1 (2 chains/mt)
        floatx4 acc0[2], acc1[2];
#pragma unroll
        for (int mt = 0; mt < 2; ++mt) {
            acc0[mt] = (floatx4){0.f, 0.f, 0.f, 0.f};
            acc1[mt] = (floatx4){0.f, 0.f, 0.f, 0.f};
        }
#pragma unroll
        for (int kb = 0; kb < 8; kb += 2) {
            short8 bf0 = *(const short8*)(bp + (kb * 4 + quad) * 256 + l15 * 16);
            short8 bf1 = *(const short8*)(bp + ((kb + 1) * 4 + quad) * 256 + l15 * 16);
#pragma unroll
            for (int mt = 0; mt < 2; ++mt) {
                acc0[mt] = __builtin_amdgcn_mfma_f32_16x16x32_bf16(wf[mt][kb], bf0, acc0[mt], 0, 0, 0);
                acc1[mt] = __builtin_amdgcn_mfma_f32_16x16x32_bf16(wf[mt][kb + 1], bf1, acc1[mt], 0, 0, 0);
            }
        }
        {
            short8 bf0 = *(const short8*)(bp + (8 * 4 + quad) * 256 + l15 * 16);
            short8 bf1 = *(const short8*)(bp + (9 * 4 + quad) * 256 + l15 * 16);
#pragma unroll
            for (int mt = 0; mt < 2; ++mt) {
                acc0[mt] = __builtin_amdgcn_mfma_f32_16x16x32_bf16(wi[mt][0], bf0, acc0[mt], 0, 0, 0);
                acc1[mt] = __builtin_amdgcn_mfma_f32_16x16x32_bf16(wi[mt][1], bf1, acc1[mt], 0, 0, 0);
            }
        }
#pragma unroll
        for (int mt = 0; mt < 2; ++mt) {
            y[mt].x = fmaxf(acc0[mt][0] + acc1[mt][0] + bias[mt].x, 0.f);
            y[mt].y = fmaxf(acc0[mt][1] + acc1[mt][1] + bias[mt].y, 0.f);
            y[mt].z = fmaxf(acc0[mt][2] + acc1[mt][2] + bias[mt].z, 0.f);
            y[mt].w = fmaxf(acc0[mt][3] + acc1[mt][3] + bias[mt].w, 0.f);
        }
        if (t < 255) {
#pragma unroll
            for (int mt = 0; mt < 2; ++mt) {
                const int c0 = w * 32 + mt * 16 + quad * 4;
                uint2 u2;
                u2.x = cvtpk_bf16(y[mt].x, y[mt].y);
                u2.y = cvtpk_bf16(y[mt].z, y[mt].w);
                *(uint2*)(bn + (c0 >> 3) * 256 + l15 * 16 + (c0 & 7) * 2) = u2;
            }
            if (tid < 256) {
                uint2 u2;
                u2.x = cvtpk_bf16(xv_n.x, xv_n.y);
                u2.y = cvtpk_bf16(xv_n.z, xv_n.w);
                *(uint2*)(bn + (32 + (o4 >> 1)) * 256 + bq * 16 + (o4 & 1) * 8) = u2;
            }
        }
        barrier_lgkm();
        p ^= 1;
        xv_n = xv_f;
    }
#pragma unroll
    for (int mt = 0; mt < 2; ++mt) {
        const int j0 = w * 32 + mt * 16 + quad * 4;
#pragma unroll
        for (int r = 0; r < 4; ++r)
            ctx_out[(size_t)(g * 16 + l15) * 256 + j0 + r] = (&y[mt].x)[r];
    }
}

// ---------------------------------------------------------------------------
// BIG GEMM (FP16 A/B): M=32768,N=512,K=16448, scale folded into A-fragments.
// 256 thr / 4 waves, block tile 256x128, wave tile 64m x 128n (mt=4).
// BK=128, LDS dbuf (2x32 KB), glds(16B) prefetch, grid 512 (2 blocks/CU),
// XCD swizzle by=gidx&3. FROZEN at R12 (407us, MfmaUtil 66, issue-saturated).
// ---------------------------------------------------------------------------
__global__ __launch_bounds__(256, 2) void k_big(const ushort_t* __restrict__ xbf,
                                                const ushort_t* __restrict__ WbT,
                                                const float* __restrict__ CTXT,
                                                ushort_t* __restrict__ hbf) {
    __shared__ __align__(16) ushort_t Bt[2 * 128 * 128];   // 64 KB
    const int tid = threadIdx.x;
    const int lane = tid & 63, w = tid >> 6;               // 4 waves
    const int l15 = lane & 15, quad = lane >> 4;
    const int gidx = blockIdx.x;
    const int by = gidx & 3;                               // xcd = gidx&7
    const int bx = (gidx >> 3) * 2 + ((gidx >> 2) & 1);    // 0..127
    const int m0 = bx * 256, n0 = by * 128;
    const int mrb = m0 + w * 64 + l15;                     // mt=0 A-row

    short8 afr[4][2];                                      // [mt][ks]: f16 x row frag
#pragma unroll
    for (int mt = 0; mt < 4; ++mt) {
        afr[mt][0] = *(const short8*)(xbf + (size_t)(mrb + mt * 16) * 64 + quad * 8);
        afr[mt][1] = *(const short8*)(xbf + (size_t)(mrb + mt * 16) * 64 + 32 + quad * 8);
    }

    floatx4 acc[4][8];
#pragma unroll
    for (int mt = 0; mt < 4; ++mt)
#pragma unroll
        for (int nt = 0; nt < 8; ++nt) acc[mt][nt] = (floatx4){0.f, 0.f, 0.f, 0.f};

    // hoisted LDS read bases: byte addr = p*32768 + lbase[g] + nt*4096,
    // lbase[g] = l15*256 + (((g>>1)*8 + (g&1)*4 + quad) ^ l15)*16
    uint_t lbase[4];
#pragma unroll
    for (int g2 = 0; g2 < 4; ++g2)
        lbase[g2] = (uint_t)(l15 * 256 + ((((g2 >> 1) * 8 + (g2 & 1) * 4 + quad) ^ l15) * 16));

    // staging: granule G = q*256 + tid (q 0..7); nr = q*16 + (tid>>4),
    // slot k8 = l15 ^ (tid>>4) — same for all q -> one pointer.
    const int r0 = tid >> 4;                               // 0..15
    const ushort_t* gq0 = WbT + (size_t)(n0 + r0) * 16448 + (size_t)(l15 ^ r0) * 8;
    const size_t QSH16 = (size_t)16 * 16448;               // +16 rows (ushorts)
    ushort_t* lqb = Bt + w * 512;                          // wave-uniform base
#pragma unroll
    for (int q = 0; q < 8; ++q)                            // tile 0 -> buf 0
        glds16(gq0 + q * QSH16, lqb + q * 2048);

    // scales, packed f16x2 broadcast: s2[mt][h]
    uint_t s2[4][2];
    {
        const float* cp0 = CTXT + (size_t)mrb * 2;
#pragma unroll
        for (int mt = 0; mt < 4; ++mt) {
            float2 sc = *(const float2*)(cp0 + mt * 32);
            s2[mt][0] = bcast_h2(sc.x);
            s2[mt][1] = bcast_h2(sc.y);
        }
    }
    const float* cps = CTXT + (size_t)mrb * 2 + 65536;     // next pair-row

    const ushort_t* gqk = gq0;                             // moving K pointer
    for (int kk = 0; kk < 129; ++kk) {
        const int p = kk & 1;
        __syncthreads();                                   // tile kk resident
        if (kk < 128) {                                    // prefetch tile kk+1
            gqk += 128;
            ushort_t* ln_ = Bt + (p ^ 1) * 16384 + w * 512;
#pragma unroll
            for (int q = 0; q < 8; ++q)
                glds16(gqk + q * QSH16, ln_ + q * 2048);
        }
        uint_t s2n[4][2];
        if (kk + 1 < 128) {
#pragma unroll
            for (int mt = 0; mt < 4; ++mt) {
                float2 sc = *(const float2*)(cps + mt * 32);
                s2n[mt][0] = bcast_h2(sc.x);
                s2n[mt][1] = bcast_h2(sc.y);
            }
            cps += 65536;
        } else {
#pragma unroll
            for (int mt = 0; mt < 4; ++mt) { s2n[mt][0] = 0x3c003c00u; s2n[mt][1] = 0x3c003c00u; }
        }
        const char* bbase = (const char*)Bt + (p << 15);   // p*32768
        if (kk < 128) {
            // software pipeline: scale group g+1 while group g's MFMAs issue
            short8 a0 = scale8h(afr[0][0], s2[0][0]);
            short8 a1 = scale8h(afr[1][0], s2[1][0]);
            short8 a2 = scale8h(afr[2][0], s2[2][0]);
            short8 a3 = scale8h(afr[3][0], s2[3][0]);
#pragma unroll
            for (int g2 = 0; g2 < 4; ++g2) {
                short8 n0_, n1_, n2_, n3_;
                if (g2 < 3) {
                    const int gn = g2 + 1, hn = gn >> 1, ksn = gn & 1;
                    n0_ = scale8h(afr[0][ksn], s2[0][hn]);
                    n1_ = scale8h(afr[1][ksn], s2[1][hn]);
                    n2_ = scale8h(afr[2][ksn], s2[2][hn]);
                    n3_ = scale8h(afr[3][ksn], s2[3][hn]);
                }
                const char* bg = bbase + lbase[g2];
#pragma unroll
                for (int nt = 0; nt < 8; ++nt) {
                    short8 b = *(const short8*)(bg + nt * 4096);
                    acc[0][nt] = __builtin_amdgcn_mfma_f32_16x16x32_f16(as_h8(a0), as_h8(b), acc[0][nt], 0, 0, 0);
                    acc[1][nt] = __builtin_amdgcn_mfma_f32_16x16x32_f16(as_h8(a1), as_h8(b), acc[1][nt], 0, 0, 0);
                    acc[2][nt] = __builtin_amdgcn_mfma_f32_16x16x32_f16(as_h8(a2), as_h8(b), acc[2][nt], 0, 0, 0);
                    acc[3][nt] = __builtin_amdgcn_mfma_f32_16x16x32_f16(as_h8(a3), as_h8(b), acc[3][nt], 0, 0, 0);
                }
                if (g2 < 3) { a0 = n0_; a1 = n1_; a2 = n2_; a3 = n3_; }
            }
        } else {                                           // bias block, scale=1
#pragma unroll
            for (int ks = 0; ks < 2; ++ks) {
                const char* bg = bbase + lbase[ks];        // g=ks (h=0)
#pragma unroll
                for (int nt = 0; nt < 8; ++nt) {
                    short8 b = *(const short8*)(bg + nt * 4096);
#pragma unroll
                    for (int mt = 0; mt < 4; ++mt)
                        acc[mt][nt] = __builtin_amdgcn_mfma_f32_16x16x32_f16(as_h8(afr[mt][ks]), as_h8(b), acc[mt][nt], 0, 0, 0);
                }
            }
        }
#pragma unroll
        for (int mt = 0; mt < 4; ++mt) { s2[mt][0] = s2n[mt][0]; s2[mt][1] = s2n[mt][1]; }
    }
    // epilogue: C/D col = n0+nt*16+l15, row = m0 + w*64 + mt*16 + quad*4 + r
#pragma unroll
    for (int mt = 0; mt < 4; ++mt)
#pragma unroll
        for (int nt = 0; nt < 8; ++nt) {
            const int col = n0 + nt * 16 + l15;
#pragma unroll
            for (int r = 0; r < 4; ++r) {
                const int row = m0 + w * 64 + mt * 16 + quad * 4 + r;
                hbf[(size_t)row * 512 + col] = f2bf(fmaxf(acc[mt][nt][r], 0.f));
            }
        }
}

// ---------------------------------------------------------------------------
// Generic bf16 NT GEMM: C[m,n] = sum_k A[m,k]*B[n,k] + bias[n]
// ---------------------------------------------------------------------------
template <bool OUTF32>
__global__ __launch_bounds__(256, 2) void k_gemm_nt(const ushort_t* __restrict__ A,
                                                    const ushort_t* __restrict__ Bm,
                                                    const float* __restrict__ bias,
                                                    ushort_t* __restrict__ outb,
                                                    float* __restrict__ outf,
                                                    int K, int Nst) {
    __shared__ __align__(16) ushort_t At[128 * 72];
    __shared__ __align__(16) ushort_t Bt[128 * 72];
    const int tid = threadIdx.x;
    const int lane = tid & 63, w = tid >> 6;
    const int wm = w & 1, wn = w >> 1;
    const int l15 = lane & 15, quad = lane >> 4;
    const int m0 = blockIdx.x * 128, n0 = blockIdx.y * 128;

    const int r_l = tid >> 1, kh = (tid & 1) * 32;
    const ushort_t* gA = A + (size_t)(m0 + r_l) * K + kh;
    const ushort_t* gB = Bm + (size_t)(n0 + r_l) * K + kh;
    ushort_t* lA = &At[r_l * 72 + kh];
    ushort_t* lB = &Bt[r_l * 72 + kh];

    uint4 ra0 = *(const uint4*)(gA + 0), ra1 = *(const uint4*)(gA + 8);
    uint4 ra2 = *(const uint4*)(gA + 16), ra3 = *(const uint4*)(gA + 24);
    uint4 rb0 = *(const uint4*)(gB + 0), rb1 = *(const uint4*)(gB + 8);
    uint4 rb2 = *(const uint4*)(gB + 16), rb3 = *(const uint4*)(gB + 24);

    floatx4 acc[4][4];
#pragma unroll
    for (int i = 0; i < 4; ++i)
#pragma unroll
        for (int j = 0; j < 4; ++j) acc[i][j] = (floatx4){0.f, 0.f, 0.f, 0.f};

    const int niter = K >> 6;
    for (int kb = 0; kb < niter; ++kb) {
        __syncthreads();
        *(uint4*)(lA + 0) = ra0;  *(uint4*)(lA + 8) = ra1;
        *(uint4*)(lA + 16) = ra2; *(uint4*)(lA + 24) = ra3;
        *(uint4*)(lB + 0) = rb0;  *(uint4*)(lB + 8) = rb1;
        *(uint4*)(lB + 16) = rb2; *(uint4*)(lB + 24) = rb3;
        __syncthreads();
        if (kb + 1 < niter) {
            const ushort_t* ga = gA + (size_t)(kb + 1) * 64;
            const ushort_t* gb = gB + (size_t)(kb + 1) * 64;
            ra0 = *(const uint4*)(ga + 0);  ra1 = *(const uint4*)(ga + 8);
            ra2 = *(const uint4*)(ga + 16); ra3 = *(const uint4*)(ga + 24);
            rb0 = *(const uint4*)(gb + 0);  rb1 = *(const uint4*)(gb + 8);
            rb2 = *(const uint4*)(gb + 16); rb3 = *(const uint4*)(gb + 24);
        }
        short8 av[4][2];
#pragma unroll
        for (int mt = 0; mt < 4; ++mt) {
            const int mr2 = wm * 64 + mt * 16 + l15;
            av[mt][0] = *(const short8*)(&At[mr2 * 72 + quad * 8]);
            av[mt][1] = *(const short8*)(&At[mr2 * 72 + 32 + quad * 8]);
        }
#pragma unroll
        for (int nt = 0; nt < 4; ++nt) {
            const int nr = wn * 64 + nt * 16 + l15;
            short8 b0 = *(const short8*)(&Bt[nr * 72 + quad * 8]);
            short8 b1 = *(const short8*)(&Bt[nr * 72 + 32 + quad * 8]);
#pragma unroll
            for (int mt = 0; mt < 4; ++mt) {
                acc[mt][nt] = __builtin_amdgcn_mfma_f32_16x16x32_bf16(av[mt][0], b0, acc[mt][nt], 0, 0, 0);
                acc[mt][nt] = __builtin_amdgcn_mfma_f32_16x16x32_bf16(av[mt][1], b1, acc[mt][nt], 0, 0, 0);
            }
        }
    }
#pragma unroll
    for (int mt = 0; mt < 4; ++mt)
#pragma unroll
        for (int nt = 0; nt < 4; ++nt) {
            const int col = n0 + wn * 64 + nt * 16 + l15;
            const float bb = bias[col];
#pragma unroll
            for (int r = 0; r < 4; ++r) {
                const int row = m0 + wm * 64 + mt * 16 + quad * 4 + r;
                const float v = acc[mt][nt][r] + bb;
                if (OUTF32) outf[(size_t)row * Nst + col] = v;
                else        outb[(size_t)row * Nst + col] = f2bf(v);
            }
        }
}

// ---------------------------------------------------------------------------
// LayerNorm + residual: z = h + relu( LN(hn)*g + b ), in-place over hbf.
// ---------------------------------------------------------------------------
__global__ __launch_bounds__(256, 1) void k_ln(const ushort_t* __restrict__ hn,
                                               ushort_t* __restrict__ h,
                                               const float* __restrict__ g,
                                               const float* __restrict__ bb) {
    const int tid = threadIdx.x;
    const int lane = tid & 63;
    const int row = blockIdx.x * 4 + (tid >> 6);
    const uint4 hv = *(const uint4*)(hn + (size_t)row * 512 + lane * 8);
    float f[8];
    f[0] = blo(hv.x); f[1] = bhi(hv.x); f[2] = blo(hv.y); f[3] = bhi(hv.y);
    f[4] = blo(hv.z); f[5] = bhi(hv.z); f[6] = blo(hv.w); f[7] = bhi(hv.w);
    float s = 0.f, s2 = 0.f;
#pragma unroll
    for (int j = 0; j < 8; ++j) { s += f[j]; s2 = fmaf(f[j], f[j], s2); }
#pragma unroll
    for (int o = 32; o >= 1; o >>= 1) { s += __shfl_xor(s, o, 64); s2 += __shfl_xor(s2, o, 64); }
    const float mu = s * (1.f / 512.f);
    const float var = s2 * (1.f / 512.f) - mu * mu;
    const float rs = rsqrtf(var + 1e-5f);
    const uint4 hh = *(const uint4*)(h + (size_t)row * 512 + lane * 8);
    float hf[8];
    hf[0] = blo(hh.x); hf[1] = bhi(hh.x); hf[2] = blo(hh.y); hf[3] = bhi(hh.y);
    hf[4] = blo(hh.z); hf[5] = bhi(hh.z); hf[6] = blo(hh.w); hf[7] = bhi(hh.w);
    float4 g0 = *(const float4*)(g + lane * 8);  float4 g1 = *(const float4*)(g + lane * 8 + 4);
    float4 b0 = *(const float4*)(bb + lane * 8); float4 b1 = *(const float4*)(bb + lane * 8 + 4);
    const float gv[8] = {g0.x, g0.y, g0.z, g0.w, g1.x, g1.y, g1.z, g1.w};
    const float bv[8] = {b0.x, b0.y, b0.z, b0.w, b1.x, b1.y, b1.z, b1.w};
    float z[8];
#pragma unroll
    for (int j = 0; j < 8; ++j)
        z[j] = hf[j] + fmaxf((f[j] - mu) * rs * gv[j] + bv[j], 0.f);
    uint4 o;
    o.x = pack2(z[0], z[1]); o.y = pack2(z[2], z[3]);
    o.z = pack2(z[4], z[5]); o.w = pack2(z[6], z[7]);
    *(uint4*)(h + (size_t)row * 512 + lane * 8) = o;
}

// ---------------------------------------------------------------------------
extern "C" void kernel_launch(void* const* d_in, const int* in_sizes, int n_in,
                              void* d_out, int out_size, void* d_ws, size_t ws_size,
                              hipStream_t stream) {
    const float* x    = (const float*)d_in[0];
    const float* Wcc  = (const float*)d_in[1];
    const float* bcc  = (const float*)d_in[2];
    const float* Wic  = (const float*)d_in[3];
    const float* bic  = (const float*)d_in[4];
    const float* Wmap = (const float*)d_in[5];
    const float* bmap = (const float*)d_in[6];
    const float* Whh  = (const float*)d_in[7];
    const float* bhh  = (const float*)d_in[8];
    const float* ln_g = (const float*)d_in[9];
    const float* ln_b = (const float*)d_in[10];
    const float* Who  = (const float*)d_in[11];
    const float* bho  = (const float*)d_in[12];
    float* out = (float*)d_out;

    char* wsb = (char*)d_ws;
    ushort_t* WbT  = (ushort_t*)(wsb);                    // 16,842,752 B + 1 KB pad (f16)
    ushort_t* Whhb = (ushort_t*)(wsb + 16843776);         //    524,288 (bf16)
    ushort_t* Whob = (ushort_t*)(wsb + 17368064);         //    131,072 (bf16)
    ushort_t* xbf  = (ushort_t*)(wsb + 17499136);         //  4,194,304 (f16)
    float*    CTXT = (float*)   (wsb + 21693440);         // 33,554,432 (pair layout)
    ushort_t* hbf  = (ushort_t*)(wsb + 55247872);         // 33,554,432 (h, then z)
    ushort_t* hnbf = (ushort_t*)(wsb + 88802304);         // 33,554,432 -> ~122 MB

    k_fused<<<1052, 512, 0, stream>>>(x, Wcc, bcc, Wic, bic, Wmap, bmap, Whh, Who,
                                      WbT, Whhb, Whob, xbf, CTXT, out + 4194304);
    k_big<<<512, 256, 0, stream>>>(xbf, WbT, CTXT, hbf);
    k_gemm_nt<false><<<dim3(256, 4), 256, 0, stream>>>(hbf, Whhb, bhh, hnbf, nullptr, 512, 512);
    k_ln<<<8192, 256, 0, stream>>>(hnbf, hbf, ln_g, ln_b);
    k_gemm_nt<true><<<dim3(256, 1), 256, 0, stream>>>(hbf, Whob, bho, nullptr, out, 512, 128);
}

// Round 14
// 694.209 us; speedup vs baseline: 1.0331x; 1.0170x over previous
//
#include <hip/hip_runtime.h>

// ---------------------------------------------------------------------------
// InputMapCTRNN: T=256, B=128, I=64, C=256, H=512, O=128, ALPHA=1, EPS=1e-5
//
// h[t,b,n] = relu( sum_c ctx[t,b,c]*S_c + S_bias ) -> one MFMA GEMM
//   M=32768,N=512,K=16448 with A[m,k]=ctx[m,k>>6]*x[m,k&63] generated
//   per-fragment in registers (f16 since R9).
//
// k_big: FROZEN at 407-410us (MfmaUtil 66 + VALU 31 ~= 97% issue-saturated).
// k_fused: R13 chain-split gained ~11us -> ~190us, 1780cyc/step vs ~700
//   issue. Remaining gap = ds_read/MFMA/store latency tails only partially
//   hidden at 2 waves/SIMD.
// R14: recurrence at 1024 thr / 16 waves (4/SIMD): each wave owns 16 output
//   channels (wf[8], wi[2], two 5-deep acc chains). 4-way wave interleave
//   per SIMD hides the per-wave latency tails. ~85 VGPR <= 128 cap at
//   __launch_bounds__(1024,4). Prep blocks re-indexed for 1024 thr.
// ---------------------------------------------------------------------------

typedef unsigned int  uint_t;
typedef unsigned short ushort_t;
typedef __attribute__((ext_vector_type(8))) short  short8;
typedef __attribute__((ext_vector_type(4))) short  short4v;
typedef __attribute__((ext_vector_type(4))) float  floatx4;
typedef _Float16 half8 __attribute__((ext_vector_type(8)));

__device__ __forceinline__ ushort_t f2bf(float f) {
    uint_t u = __float_as_uint(f);
    u = (u + 0x7fffu + ((u >> 16) & 1u)) >> 16;   // RNE
    return (ushort_t)u;
}
__device__ __forceinline__ ushort_t f2h(float f) {
    union { _Float16 h; ushort_t u; } c;
    c.h = (_Float16)f;                             // v_cvt_f16_f32, RNE
    return c.u;
}
__device__ __forceinline__ uint_t pack2(float a, float b) {
    return (uint_t)f2bf(a) | ((uint_t)f2bf(b) << 16);
}
__device__ __forceinline__ float blo(uint_t u) { return __uint_as_float(u << 16); }
__device__ __forceinline__ float bhi(uint_t u) { return __uint_as_float(u & 0xffff0000u); }

__device__ __forceinline__ void glds16(const void* g, void* l) {
    __builtin_amdgcn_global_load_lds(
        (const __attribute__((address_space(1))) unsigned int*)g,
        (__attribute__((address_space(3))) unsigned int*)l, 16, 0, 0);
}

// barrier draining ONLY LDS ops; global stores/loads stay in flight.
__device__ __forceinline__ void barrier_lgkm() {
    asm volatile("s_waitcnt lgkmcnt(0)" ::: "memory");
    __builtin_amdgcn_s_barrier();
}

// two f32 -> packed bf16 pair, 1 inst (RNE)
__device__ __forceinline__ uint_t cvtpk_bf16(float a, float b) {
    uint_t r;
    asm("v_cvt_pk_bf16_f32 %0, %1, %2" : "=v"(r) : "v"(a), "v"(b));
    return r;
}
// f32 scalar -> packed f16 pair (s,s), 1 inst (RTZ; scale precision ample)
__device__ __forceinline__ uint_t bcast_h2(float s) {
    uint_t r;
    asm("v_cvt_pkrtz_f16_f32 %0, %1, %2" : "=v"(r) : "v"(s), "v"(s));
    return r;
}
// scale 8 packed f16 by f16x2 broadcast scalar: 4 x v_pk_mul_f16
__device__ __forceinline__ short8 scale8h(short8 a, uint_t s2) {
    union { short8 v; uint_t u[4]; } in, out;
    in.v = a;
#pragma unroll
    for (int q = 0; q < 4; ++q)
        asm("v_pk_mul_f16 %0, %1, %2" : "=v"(out.u[q]) : "v"(in.u[q]), "v"(s2));
    return out.v;
}
__device__ __forceinline__ half8 as_h8(short8 s) {
    union { short8 a; half8 b; } c; c.a = s; return c.b;
}

// ---------------------------------------------------------------------------
// FUSED (1024 thr): blocks 0..7 = sequential ctx recurrence, 16 waves
// (4/SIMD); wave w owns output channels [w*16, w*16+16). blocks 8..1051 =
// prep (WbT transpose -> F16, Whh/Who -> bf16, x -> F16).
// CTXT layout: CTXT2[c>>1][m][c&1] (pair-rows of 65536 floats).
// ---------------------------------------------------------------------------
__global__ __launch_bounds__(1024, 4) void k_fused(
        const float* __restrict__ x, const float* __restrict__ Wcc,
        const float* __restrict__ bcc, const float* __restrict__ Wic,
        const float* __restrict__ bic, const float* __restrict__ Wmap,
        const float* __restrict__ bmap, const float* __restrict__ Whh,
        const float* __restrict__ Who,
        ushort_t* WbT, ushort_t* Whhb, ushort_t* Whob, ushort_t* xbf,
        float* __restrict__ CTXT, float* __restrict__ ctx_out) {
    __shared__ __align__(16) char smem[32896];   // union: prep 32896 B / rec 20480 B
    const int tid = threadIdx.x;
    const int bid = blockIdx.x;

    if (bid >= 8) {
        const int pb = bid - 8;
        if (pb < 512) {                      // WbT[n][c*64+i] = f16(Wmap[n*64+i][c])
            float* tl = (float*)smem;        // 32*257 floats
            const int n = pb;
            for (int p2 = 0; p2 < 2; ++p2) {
                if (p2) barrier_lgkm();
                if (tid < 256) {
#pragma unroll
                    for (int k = 0; k < 32; ++k)
                        tl[k * 257 + tid] = Wmap[(size_t)(n * 64 + p2 * 32 + k) * 256 + tid];
                }
                barrier_lgkm();
                if (tid < 256) {
#pragma unroll
                    for (int k2 = 0; k2 < 32; ++k2) {
                        int o = k2 * 256 + tid;
                        int il = o & 31, c = o >> 5;
                        WbT[(size_t)n * 16448 + c * 64 + p2 * 32 + il] = f2h(tl[il * 257 + c]);
                    }
                }
            }
            if (tid < 64) WbT[(size_t)n * 16448 + 16384 + tid] = f2h(bmap[n * 64 + tid]);
        } else if (pb < 528) {
            size_t base = (size_t)(pb - 512) * 16384;
#pragma unroll
            for (int k = 0; k < 16; ++k) { size_t i = base + k * 1024 + tid; Whhb[i] = f2bf(Whh[i]); }
        } else if (pb < 532) {
            size_t base = (size_t)(pb - 528) * 16384;
#pragma unroll
            for (int k = 0; k < 16; ++k) { size_t i = base + k * 1024 + tid; Whob[i] = f2bf(Who[i]); }
        } else {
            size_t base = (size_t)(pb - 532) * 4096;
#pragma unroll
            for (int k = 0; k < 4; ++k) { size_t i = base + k * 1024 + tid; xbf[i] = f2h(x[i]); }
        }
        return;
    }

    // ---------------- recurrence: block g owns samples [g*16, g*16+16) ------
    // 16 waves; wave w owns output channels [w*16, w*16+16)
    char* bufs = smem;                          // 2 x 10240 B
    const int g = bid;
    const int lane = tid & 63, w = tid >> 6;
    const int l15 = lane & 15, quad = lane >> 4;
    const int bq = (tid & 255) >> 4, o4 = tid & 15;  // x-staging role (tid<256)

    // A-fragments: Wcc (kb 0..7) + Wic (kb 8..9); row j = w*16+l15
    short8 wf[8], wi[2];
    {
        const int j = w * 16 + l15;
#pragma unroll
        for (int kb = 0; kb < 8; ++kb) {
            const float* src = Wcc + (size_t)j * 256 + kb * 32 + quad * 8;
            float4 a = *(const float4*)src;
            float4 b = *(const float4*)(src + 4);
            short8 s;
            s[0] = (short)f2bf(a.x); s[1] = (short)f2bf(a.y);
            s[2] = (short)f2bf(a.z); s[3] = (short)f2bf(a.w);
            s[4] = (short)f2bf(b.x); s[5] = (short)f2bf(b.y);
            s[6] = (short)f2bf(b.z); s[7] = (short)f2bf(b.w);
            wf[kb] = s;
        }
#pragma unroll
        for (int kb = 0; kb < 2; ++kb) {
            const float* src = Wic + (size_t)j * 64 + kb * 32 + quad * 8;
            float4 a = *(const float4*)src;
            float4 b = *(const float4*)(src + 4);
            short8 s;
            s[0] = (short)f2bf(a.x); s[1] = (short)f2bf(a.y);
            s[2] = (short)f2bf(a.z); s[3] = (short)f2bf(a.w);
            s[4] = (short)f2bf(b.x); s[5] = (short)f2bf(b.y);
            s[6] = (short)f2bf(b.z); s[7] = (short)f2bf(b.w);
            wi[kb] = s;
        }
    }
    float4 bias;
    {
        const int j0 = w * 16 + quad * 4;
        float4 b1 = *(const float4*)(bic + j0);
        float4 b2 = *(const float4*)(bcc + j0);
        bias = (float4){b1.x + b2.x, b1.y + b2.y, b1.z + b2.z, b1.w + b2.w};
    }
    // init buf0: ctx=0 (rows 0..31 = 8192 B), x_0 (rows 32..39)
    if (tid < 512) *(uint4*)(bufs + tid * 16) = (uint4){0, 0, 0, 0};
    if (tid < 256) {
        float4 xv = *(const float4*)(x + (size_t)(g * 16 + bq) * 64 + o4 * 4);
        uint2 u2;
        u2.x = cvtpk_bf16(xv.x, xv.y);
        u2.y = cvtpk_bf16(xv.z, xv.w);
        *(uint2*)(bufs + (32 + (o4 >> 1)) * 256 + bq * 16 + (o4 & 1) * 8) = u2;
    }
    float4 y = (float4){0.f, 0.f, 0.f, 0.f};
    // 2-step-ahead x pipeline: xv_n holds x[t+1] during step t
    float4 xv_n, xv_f;
    if (tid < 256)
        xv_n = *(const float4*)(x + (size_t)(128 + g * 16 + bq) * 64 + o4 * 4);
    barrier_lgkm();

    int p = 0;
#pragma unroll 1
    for (int t = 0; t < 256; ++t) {
        char* bp = bufs + p * 10240;
        char* bn = bufs + (p ^ 1) * 10240;
        // CTXT2[c>>1][m][c&1] = ctx entering step t (= y); m = t*128+g*16+l15
        {
            const int j0 = w * 16 + quad * 4;               // multiple of 4
            const size_t mi = (size_t)(t * 128 + g * 16 + l15) * 2;
            const size_t pr = (size_t)(j0 >> 1) * 65536 + mi;
            *(float2*)(CTXT + pr)         = (float2){y.x, y.y};
            *(float2*)(CTXT + pr + 65536) = (float2){y.z, y.w};
        }
        if (t < 254 && tid < 256)                           // load x[t+2]
            xv_f = *(const float4*)(x + (size_t)((t + 2) * 128 + g * 16 + bq) * 64 + o4 * 4);
        // split accumulators: even kb -> acc0, odd kb -> acc1
        floatx4 acc0 = (floatx4){0.f, 0.f, 0.f, 0.f};
        floatx4 acc1 = (floatx4){0.f, 0.f, 0.f, 0.f};
#pragma unroll
        for (int kb = 0; kb < 8; kb += 2) {
            short8 bf0 = *(const short8*)(bp + (kb * 4 + quad) * 256 + l15 * 16);
            short8 bf1 = *(const short8*)(bp + ((kb + 1) * 4 + quad) * 256 + l15 * 16);
            acc0 = __builtin_amdgcn_mfma_f32_16x16x32_bf16(wf[kb], bf0, acc0, 0, 0, 0);
            acc1 = __builtin_amdgcn_mfma_f32_16x16x32_bf16(wf[kb + 1], bf1, acc1, 0, 0, 0);
        }
        {
            short8 bf0 = *(const short8*)(bp + (8 * 4 + quad) * 256 + l15 * 16);
            short8 bf1 = *(const short8*)(bp + (9 * 4 + quad) * 256 + l15 * 16);
            acc0 = __builtin_amdgcn_mfma_f32_16x16x32_bf16(wi[0], bf0, acc0, 0, 0, 0);
            acc1 = __builtin_amdgcn_mfma_f32_16x16x32_bf16(wi[1], bf1, acc1, 0, 0, 0);
        }
        y.x = fmaxf(acc0[0] + acc1[0] + bias.x, 0.f);
        y.y = fmaxf(acc0[1] + acc1[1] + bias.y, 0.f);
        y.z = fmaxf(acc0[2] + acc1[2] + bias.z, 0.f);
        y.w = fmaxf(acc0[3] + acc1[3] + bias.w, 0.f);
        if (t < 255) {
            {
                const int c0 = w * 16 + quad * 4;
                uint2 u2;
                u2.x = cvtpk_bf16(y.x, y.y);
                u2.y = cvtpk_bf16(y.z, y.w);
                *(uint2*)(bn + (c0 >> 3) * 256 + l15 * 16 + (c0 & 7) * 2) = u2;
            }
            if (tid < 256) {
                uint2 u2;
                u2.x = cvtpk_bf16(xv_n.x, xv_n.y);
                u2.y = cvtpk_bf16(xv_n.z, xv_n.w);
                *(uint2*)(bn + (32 + (o4 >> 1)) * 256 + bq * 16 + (o4 & 1) * 8) = u2;
            }
        }
        barrier_lgkm();
        p ^= 1;
        xv_n = xv_f;
    }
    {
        const int j0 = w * 16 + quad * 4;
#pragma unroll
        for (int r = 0; r < 4; ++r)
            ctx_out[(size_t)(g * 16 + l15) * 256 + j0 + r] = (&y.x)[r];
    }
}

// ---------------------------------------------------------------------------
// BIG GEMM (FP16 A/B): M=32768,N=512,K=16448, scale folded into A-fragments.
// 256 thr / 4 waves, block tile 256x128, wave tile 64m x 128n (mt=4).
// BK=128, LDS dbuf (2x32 KB), glds(16B) prefetch, grid 512 (2 blocks/CU),
// XCD swizzle by=gidx&3. FROZEN at R12 (407us, MfmaUtil 66, issue-saturated).
// ---------------------------------------------------------------------------
__global__ __launch_bounds__(256, 2) void k_big(const ushort_t* __restrict__ xbf,
                                                const ushort_t* __restrict__ WbT,
                                                const float* __restrict__ CTXT,
                                                ushort_t* __restrict__ hbf) {
    __shared__ __align__(16) ushort_t Bt[2 * 128 * 128];   // 64 KB
    const int tid = threadIdx.x;
    const int lane = tid & 63, w = tid >> 6;               // 4 waves
    const int l15 = lane & 15, quad = lane >> 4;
    const int gidx = blockIdx.x;
    const int by = gidx & 3;                               // xcd = gidx&7
    const int bx = (gidx >> 3) * 2 + ((gidx >> 2) & 1);    // 0..127
    const int m0 = bx * 256, n0 = by * 128;
    const int mrb = m0 + w * 64 + l15;                     // mt=0 A-row

    short8 afr[4][2];                                      // [mt][ks]: f16 x row frag
#pragma unroll
    for (int mt = 0; mt < 4; ++mt) {
        afr[mt][0] = *(const short8*)(xbf + (size_t)(mrb + mt * 16) * 64 + quad * 8);
        afr[mt][1] = *(const short8*)(xbf + (size_t)(mrb + mt * 16) * 64 + 32 + quad * 8);
    }

    floatx4 acc[4][8];
#pragma unroll
    for (int mt = 0; mt < 4; ++mt)
#pragma unroll
        for (int nt = 0; nt < 8; ++nt) acc[mt][nt] = (floatx4){0.f, 0.f, 0.f, 0.f};

    // hoisted LDS read bases: byte addr = p*32768 + lbase[g] + nt*4096,
    // lbase[g] = l15*256 + (((g>>1)*8 + (g&1)*4 + quad) ^ l15)*16
    uint_t lbase[4];
#pragma unroll
    for (int g2 = 0; g2 < 4; ++g2)
        lbase[g2] = (uint_t)(l15 * 256 + ((((g2 >> 1) * 8 + (g2 & 1) * 4 + quad) ^ l15) * 16));

    // staging: granule G = q*256 + tid (q 0..7); nr = q*16 + (tid>>4),
    // slot k8 = l15 ^ (tid>>4) — same for all q -> one pointer.
    const int r0 = tid >> 4;                               // 0..15
    const ushort_t* gq0 = WbT + (size_t)(n0 + r0) * 16448 + (size_t)(l15 ^ r0) * 8;
    const size_t QSH16 = (size_t)16 * 16448;               // +16 rows (ushorts)
    ushort_t* lqb = Bt + w * 512;                          // wave-uniform base
#pragma unroll
    for (int q = 0; q < 8; ++q)                            // tile 0 -> buf 0
        glds16(gq0 + q * QSH16, lqb + q * 2048);

    // scales, packed f16x2 broadcast: s2[mt][h]
    uint_t s2[4][2];
    {
        const float* cp0 = CTXT + (size_t)mrb * 2;
#pragma unroll
        for (int mt = 0; mt < 4; ++mt) {
            float2 sc = *(const float2*)(cp0 + mt * 32);
            s2[mt][0] = bcast_h2(sc.x);
            s2[mt][1] = bcast_h2(sc.y);
        }
    }
    const float* cps = CTXT + (size_t)mrb * 2 + 65536;     // next pair-row

    const ushort_t* gqk = gq0;                             // moving K pointer
    for (int kk = 0; kk < 129; ++kk) {
        const int p = kk & 1;
        __syncthreads();                                   // tile kk resident
        if (kk < 128) {                                    // prefetch tile kk+1
            gqk += 128;
            ushort_t* ln_ = Bt + (p ^ 1) * 16384 + w * 512;
#pragma unroll
            for (int q = 0; q < 8; ++q)
                glds16(gqk + q * QSH16, ln_ + q * 2048);
        }
        uint_t s2n[4][2];
        if (kk + 1 < 128) {
#pragma unroll
            for (int mt = 0; mt < 4; ++mt) {
                float2 sc = *(const float2*)(cps + mt * 32);
                s2n[mt][0] = bcast_h2(sc.x);
                s2n[mt][1] = bcast_h2(sc.y);
            }
            cps += 65536;
        } else {
#pragma unroll
            for (int mt = 0; mt < 4; ++mt) { s2n[mt][0] = 0x3c003c00u; s2n[mt][1] = 0x3c003c00u; }
        }
        const char* bbase = (const char*)Bt + (p << 15);   // p*32768
        if (kk < 128) {
            // software pipeline: scale group g+1 while group g's MFMAs issue
            short8 a0 = scale8h(afr[0][0], s2[0][0]);
            short8 a1 = scale8h(afr[1][0], s2[1][0]);
            short8 a2 = scale8h(afr[2][0], s2[2][0]);
            short8 a3 = scale8h(afr[3][0], s2[3][0]);
#pragma unroll
            for (int g2 = 0; g2 < 4; ++g2) {
                short8 n0_, n1_, n2_, n3_;
                if (g2 < 3) {
                    const int gn = g2 + 1, hn = gn >> 1, ksn = gn & 1;
                    n0_ = scale8h(afr[0][ksn], s2[0][hn]);
                    n1_ = scale8h(afr[1][ksn], s2[1][hn]);
                    n2_ = scale8h(afr[2][ksn], s2[2][hn]);
                    n3_ = scale8h(afr[3][ksn], s2[3][hn]);
                }
                const char* bg = bbase + lbase[g2];
#pragma unroll
                for (int nt = 0; nt < 8; ++nt) {
                    short8 b = *(const short8*)(bg + nt * 4096);
                    acc[0][nt] = __builtin_amdgcn_mfma_f32_16x16x32_f16(as_h8(a0), as_h8(b), acc[0][nt], 0, 0, 0);
                    acc[1][nt] = __builtin_amdgcn_mfma_f32_16x16x32_f16(as_h8(a1), as_h8(b), acc[1][nt], 0, 0, 0);
                    acc[2][nt] = __builtin_amdgcn_mfma_f32_16x16x32_f16(as_h8(a2), as_h8(b), acc[2][nt], 0, 0, 0);
                    acc[3][nt] = __builtin_amdgcn_mfma_f32_16x16x32_f16(as_h8(a3), as_h8(b), acc[3][nt], 0, 0, 0);
                }
                if (g2 < 3) { a0 = n0_; a1 = n1_; a2 = n2_; a3 = n3_; }
            }
        } else {                                           // bias block, scale=1
#pragma unroll
            for (int ks = 0; ks < 2; ++ks) {
                const char* bg = bbase + lbase[ks];        // g=ks (h=0)
#pragma unroll
                for (int nt = 0; nt < 8; ++nt) {
                    short8 b = *(const short8*)(bg + nt * 4096);
#pragma unroll
                    for (int mt = 0; mt < 4; ++mt)
                        acc[mt][nt] = __builtin_amdgcn_mfma_f32_16x16x32_f16(as_h8(afr[mt][ks]), as_h8(b), acc[mt][nt], 0, 0, 0);
                }
            }
        }
#pragma unroll
        for (int mt = 0; mt < 4; ++mt) { s2[mt][0] = s2n[mt][0]; s2[mt][1] = s2n[mt][1]; }
    }
    // epilogue: C/D col = n0+nt*16+l15, row = m0 + w*64 + mt*16 + quad*4 + r
#pragma unroll
    for (int mt = 0; mt < 4; ++mt)
#pragma unroll
        for (int nt = 0; nt < 8; ++nt) {
            const int col = n0 + nt * 16 + l15;
#pragma unroll
            for (int r = 0; r < 4; ++r) {
                const int row = m0 + w * 64 + mt * 16 + quad * 4 + r;
                hbf[(size_t)row * 512 + col] = f2bf(fmaxf(acc[mt][nt][r], 0.f));
            }
        }
}

// ---------------------------------------------------------------------------
// Generic bf16 NT GEMM: C[m,n] = sum_k A[m,k]*B[n,k] + bias[n]
// ---------------------------------------------------------------------------
template <bool OUTF32>
__global__ __launch_bounds__(256, 2) void k_gemm_nt(const ushort_t* __restrict__ A,
                                                    const ushort_t* __restrict__ Bm,
                                                    const float* __restrict__ bias,
                                                    ushort_t* __restrict__ outb,
                                                    float* __restrict__ outf,
                                                    int K, int Nst) {
    __shared__ __align__(16) ushort_t At[128 * 72];
    __shared__ __align__(16) ushort_t Bt[128 * 72];
    const int tid = threadIdx.x;
    const int lane = tid & 63, w = tid >> 6;
    const int wm = w & 1, wn = w >> 1;
    const int l15 = lane & 15, quad = lane >> 4;
    const int m0 = blockIdx.x * 128, n0 = blockIdx.y * 128;

    const int r_l = tid >> 1, kh = (tid & 1) * 32;
    const ushort_t* gA = A + (size_t)(m0 + r_l) * K + kh;
    const ushort_t* gB = Bm + (size_t)(n0 + r_l) * K + kh;
    ushort_t* lA = &At[r_l * 72 + kh];
    ushort_t* lB = &Bt[r_l * 72 + kh];

    uint4 ra0 = *(const uint4*)(gA + 0), ra1 = *(const uint4*)(gA + 8);
    uint4 ra2 = *(const uint4*)(gA + 16), ra3 = *(const uint4*)(gA + 24);
    uint4 rb0 = *(const uint4*)(gB + 0), rb1 = *(const uint4*)(gB + 8);
    uint4 rb2 = *(const uint4*)(gB + 16), rb3 = *(const uint4*)(gB + 24);

    floatx4 acc[4][4];
#pragma unroll
    for (int i = 0; i < 4; ++i)
#pragma unroll
        for (int j = 0; j < 4; ++j) acc[i][j] = (floatx4){0.f, 0.f, 0.f, 0.f};

    const int niter = K >> 6;
    for (int kb = 0; kb < niter; ++kb) {
        __syncthreads();
        *(uint4*)(lA + 0) = ra0;  *(uint4*)(lA + 8) = ra1;
        *(uint4*)(lA + 16) = ra2; *(uint4*)(lA + 24) = ra3;
        *(uint4*)(lB + 0) = rb0;  *(uint4*)(lB + 8) = rb1;
        *(uint4*)(lB + 16) = rb2; *(uint4*)(lB + 24) = rb3;
        __syncthreads();
        if (kb + 1 < niter) {
            const ushort_t* ga = gA + (size_t)(kb + 1) * 64;
            const ushort_t* gb = gB + (size_t)(kb + 1) * 64;
            ra0 = *(const uint4*)(ga + 0);  ra1 = *(const uint4*)(ga + 8);
            ra2 = *(const uint4*)(ga + 16); ra3 = *(const uint4*)(ga + 24);
            rb0 = *(const uint4*)(gb + 0);  rb1 = *(const uint4*)(gb + 8);
            rb2 = *(const uint4*)(gb + 16); rb3 = *(const uint4*)(gb + 24);
        }
        short8 av[4][2];
#pragma unroll
        for (int mt = 0; mt < 4; ++mt) {
            const int mr2 = wm * 64 + mt * 16 + l15;
            av[mt][0] = *(const short8*)(&At[mr2 * 72 + quad * 8]);
            av[mt][1] = *(const short8*)(&At[mr2 * 72 + 32 + quad * 8]);
        }
#pragma unroll
        for (int nt = 0; nt < 4; ++nt) {
            const int nr = wn * 64 + nt * 16 + l15;
            short8 b0 = *(const short8*)(&Bt[nr * 72 + quad * 8]);
            short8 b1 = *(const short8*)(&Bt[nr * 72 + 32 + quad * 8]);
#pragma unroll
            for (int mt = 0; mt < 4; ++mt) {
                acc[mt][nt] = __builtin_amdgcn_mfma_f32_16x16x32_bf16(av[mt][0], b0, acc[mt][nt], 0, 0, 0);
                acc[mt][nt] = __builtin_amdgcn_mfma_f32_16x16x32_bf16(av[mt][1], b1, acc[mt][nt], 0, 0, 0);
            }
        }
    }
#pragma unroll
    for (int mt = 0; mt < 4; ++mt)
#pragma unroll
        for (int nt = 0; nt < 4; ++nt) {
            const int col = n0 + wn * 64 + nt * 16 + l15;
            const float bb = bias[col];
#pragma unroll
            for (int r = 0; r < 4; ++r) {
                const int row = m0 + wm * 64 + mt * 16 + quad * 4 + r;
                const float v = acc[mt][nt][r] + bb;
                if (OUTF32) outf[(size_t)row * Nst + col] = v;
                else        outb[(size_t)row * Nst + col] = f2bf(v);
            }
        }
}

// ---------------------------------------------------------------------------
// LayerNorm + residual: z = h + relu( LN(hn)*g + b ), in-place over hbf.
// ---------------------------------------------------------------------------
__global__ __launch_bounds__(256, 1) void k_ln(const ushort_t* __restrict__ hn,
                                               ushort_t* __restrict__ h,
                                               const float* __restrict__ g,
                                               const float* __restrict__ bb) {
    const int tid = threadIdx.x;
    const int lane = tid & 63;
    const int row = blockIdx.x * 4 + (tid >> 6);
    const uint4 hv = *(const uint4*)(hn + (size_t)row * 512 + lane * 8);
    float f[8];
    f[0] = blo(hv.x); f[1] = bhi(hv.x); f[2] = blo(hv.y); f[3] = bhi(hv.y);
    f[4] = blo(hv.z); f[5] = bhi(hv.z); f[6] = blo(hv.w); f[7] = bhi(hv.w);
    float s = 0.f, s2 = 0.f;
#pragma unroll
    for (int j = 0; j < 8; ++j) { s += f[j]; s2 = fmaf(f[j], f[j], s2); }
#pragma unroll
    for (int o = 32; o >= 1; o >>= 1) { s += __shfl_xor(s, o, 64); s2 += __shfl_xor(s2, o, 64); }
    const float mu = s * (1.f / 512.f);
    const float var = s2 * (1.f / 512.f) - mu * mu;
    const float rs = rsqrtf(var + 1e-5f);
    const uint4 hh = *(const uint4*)(h + (size_t)row * 512 + lane * 8);
    float hf[8];
    hf[0] = blo(hh.x); hf[1] = bhi(hh.x); hf[2] = blo(hh.y); hf[3] = bhi(hh.y);
    hf[4] = blo(hh.z); hf[5] = bhi(hh.z); hf[6] = blo(hh.w); hf[7] = bhi(hh.w);
    float4 g0 = *(const float4*)(g + lane * 8);  float4 g1 = *(const float4*)(g + lane * 8 + 4);
    float4 b0 = *(const float4*)(bb + lane * 8); float4 b1 = *(const float4*)(bb + lane * 8 + 4);
    const float gv[8] = {g0.x, g0.y, g0.z, g0.w, g1.x, g1.y, g1.z, g1.w};
    const float bv[8] = {b0.x, b0.y, b0.z, b0.w, b1.x, b1.y, b1.z, b1.w};
    float z[8];
#pragma unroll
    for (int j = 0; j < 8; ++j)
        z[j] = hf[j] + fmaxf((f[j] - mu) * rs * gv[j] + bv[j], 0.f);
    uint4 o;
    o.x = pack2(z[0], z[1]); o.y = pack2(z[2], z[3]);
    o.z = pack2(z[4], z[5]); o.w = pack2(z[6], z[7]);
    *(uint4*)(h + (size_t)row * 512 + lane * 8) = o;
}

// ---------------------------------------------------------------------------
extern "C" void kernel_launch(void* const* d_in, const int* in_sizes, int n_in,
                              void* d_out, int out_size, void* d_ws, size_t ws_size,
                              hipStream_t stream) {
    const float* x    = (const float*)d_in[0];
    const float* Wcc  = (const float*)d_in[1];
    const float* bcc  = (const float*)d_in[2];
    const float* Wic  = (const float*)d_in[3];
    const float* bic  = (const float*)d_in[4];
    const float* Wmap = (const float*)d_in[5];
    const float* bmap = (const float*)d_in[6];
    const float* Whh  = (const float*)d_in[7];
    const float* bhh  = (const float*)d_in[8];
    const float* ln_g = (const float*)d_in[9];
    const float* ln_b = (const float*)d_in[10];
    const float* Who  = (const float*)d_in[11];
    const float* bho  = (const float*)d_in[12];
    float* out = (float*)d_out;

    char* wsb = (char*)d_ws;
    ushort_t* WbT  = (ushort_t*)(wsb);                    // 16,842,752 B + 1 KB pad (f16)
    ushort_t* Whhb = (ushort_t*)(wsb + 16843776);         //    524,288 (bf16)
    ushort_t* Whob = (ushort_t*)(wsb + 17368064);         //    131,072 (bf16)
    ushort_t* xbf  = (ushort_t*)(wsb + 17499136);         //  4,194,304 (f16)
    float*    CTXT = (float*)   (wsb + 21693440);         // 33,554,432 (pair layout)
    ushort_t* hbf  = (ushort_t*)(wsb + 55247872);         // 33,554,432 (h, then z)
    ushort_t* hnbf = (ushort_t*)(wsb + 88802304);         // 33,554,432 -> ~122 MB

    k_fused<<<1052, 1024, 0, stream>>>(x, Wcc, bcc, Wic, bic, Wmap, bmap, Whh, Who,
                                       WbT, Whhb, Whob, xbf, CTXT, out + 4194304);
    k_big<<<512, 256, 0, stream>>>(xbf, WbT, CTXT, hbf);
    k_gemm_nt<false><<<dim3(256, 4), 256, 0, stream>>>(hbf, Whhb, bhh, hnbf, nullptr, 512, 512);
    k_ln<<<8192, 256, 0, stream>>>(hnbf, hbf, ln_g, ln_b);
    k_gemm_nt<true><<<dim3(256, 1), 256, 0, stream>>>(hbf, Whob, bho, nullptr, out, 512, 128);
}